// Round 1
// baseline (598.724 us; speedup 1.0000x reference)
//
#include <hip/hip_runtime.h>
#include <math.h>

namespace {

constexpr int PPW  = 4;                    // points per wave
constexpr int WPB  = 4;                    // waves per block
constexpr int PPB  = PPW * WPB;            // 16 points per block
constexpr int NPTS = 256 * 128;            // 32768 points total
constexpr int GRID = NPTS / PPB;           // 2048 blocks
constexpr int OUTS = 257;                  // D+1
constexpr size_t HOFF = (size_t)NPTS * OUTS;
constexpr int LSTR = 260;                  // LDS row stride (16B aligned, conflict-free b128)

__device__ __forceinline__ float dot4f(float4 a, float4 b) {
  return a.x * b.x + a.y * b.y + a.z * b.z + a.w * b.w;
}

template <int NB>
__device__ __forceinline__ void wave_reduce(float* v) {
#pragma unroll
  for (int off = 32; off > 0; off >>= 1) {
#pragma unroll
    for (int i = 0; i < NB; ++i) v[i] += __shfl_xor(v[i], off, 64);
  }
}

__global__ __launch_bounds__(256) void splmw_kernel(
    const float* __restrict__ xt, const float* __restrict__ xc,
    const float* __restrict__ xf, const float* __restrict__ xr,
    const float* __restrict__ Wt, const float* __restrict__ bt,
    const float* __restrict__ Wc, const float* __restrict__ bc,
    const float* __restrict__ Wf, const float* __restrict__ bf,
    const float* __restrict__ Wr, const float* __restrict__ br,
    const float* __restrict__ esp, const float* __restrict__ lwp,
    float* __restrict__ out) {
  __shared__ float wlds[32 * LSTR];

  const int tid  = threadIdx.x;
  const int lane = tid & 63;
  const int wv   = __builtin_amdgcn_readfirstlane(tid >> 6);  // wave-uniform
  const int pt0  = blockIdx.x * PPB + wv * PPW;

  const float ts = tanhf(esp[0]);
  // softmax of lorentz_weights
  float l0 = lwp[0], l1 = lwp[1], l2 = lwp[2], l3 = lwp[3];
  float mx = fmaxf(fmaxf(l0, l1), fmaxf(l2, l3));
  float e0 = expf(l0 - mx), e1 = expf(l1 - mx), e2 = expf(l2 - mx), e3 = expf(l3 - mx);
  float ei = 1.f / (e0 + e1 + e2 + e3);
  const float wgt[4] = {e0 * ei, e1 * ei, e2 * ei, e3 * ei};

  const float* xsarr[4] = {xt, xc, xf, xr};
  const float* Wsarr[4] = {Wt, Wc, Wf, Wr};
  const float* Bsarr[4] = {bt, bc, bf, br};

  // h[c][p]: spatial fragment (comps 4*lane..4*lane+3); x0s[c][p]: time comp (wave-uniform)
  float4 h[4][PPW];
  float  x0s[4][PPW];

#pragma unroll
  for (int c = 0; c < 4; ++c) {
    // ---- stage W_c transposed into LDS: wlds[s*LSTR + d] = W[d][s] ----
    __syncthreads();
    {
      const float* Wp = Wsarr[c];
#pragma unroll
      for (int k = 0; k < 32; ++k) {
        int idx = k * 256 + tid;                       // flat d*32+s
        wlds[(idx & 31) * LSTR + (idx >> 5)] = Wp[idx];
      }
    }
    __syncthreads();

    // ---- encode: z[d] = sum_s xs[s]*W[d][s] + b[d], 4 points per wave ----
    const float* xp = xsarr[c] + (size_t)pt0 * 32;     // wave-uniform -> s_load
    {
      float4 bv = ((const float4*)Bsarr[c])[lane];
#pragma unroll
      for (int p = 0; p < PPW; ++p) h[c][p] = bv;
    }
#pragma unroll
    for (int s4 = 0; s4 < 8; ++s4) {
      float4 q0 = *(const float4*)(xp + 4 * s4);
      float4 q1 = *(const float4*)(xp + 32 + 4 * s4);
      float4 q2 = *(const float4*)(xp + 64 + 4 * s4);
      float4 q3 = *(const float4*)(xp + 96 + 4 * s4);
      float xv[4][4] = {{q0.x, q0.y, q0.z, q0.w}, {q1.x, q1.y, q1.z, q1.w},
                        {q2.x, q2.y, q2.z, q2.w}, {q3.x, q3.y, q3.z, q3.w}};
#pragma unroll
      for (int si = 0; si < 4; ++si) {
        int s = 4 * s4 + si;
        float4 w4 = *(const float4*)&wlds[s * LSTR + 4 * lane];
#pragma unroll
        for (int p = 0; p < PPW; ++p) {
          h[c][p].x += xv[p][si] * w4.x;
          h[c][p].y += xv[p][si] * w4.y;
          h[c][p].z += xv[p][si] * w4.z;
          h[c][p].w += xv[p][si] * w4.w;
        }
      }
    }

    // ---- to_hyperbolic ----
    float pa[PPW];
#pragma unroll
    for (int p = 0; p < PPW; ++p) {
      h[c][p].x *= ts; h[c][p].y *= ts; h[c][p].z *= ts; h[c][p].w *= ts;
      pa[p] = dot4f(h[c][p], h[c][p]);
    }
    wave_reduce<PPW>(pa);
#pragma unroll
    for (int p = 0; p < PPW; ++p) {
      float n1  = sqrtf(pa[p]);
      float n1m = fmaxf(n1, 1e-8f);
      float c1  = fminf(n1m, 1.5f) / n1m;     // clip-to-1.5 scale
      float n2  = c1 * n1;                    // norm after clip
      float nsx = fmaxf(n2, 1e-9f);
      float sh  = sinhf(n2);
      float g   = sh * c1 / nsx;
      float4 v  = h[c][p];
      float4 xq = make_float4(g * v.x, g * v.y, g * v.z, g * v.w);
      float sxr = sh * n2 / nsx;              // ||xr||
      float xx0 = sqrtf(1.f + sxr * sxr);     // projx
      h[c][p]   = xq;
      x0s[c][p] = xx0;
      float* o = out + (size_t)c * HOFF + (size_t)(pt0 + p) * OUTS;
      if (lane == 0) o[0] = xx0;
      int base = 1 + 4 * lane;
      o[base] = xq.x; o[base + 1] = xq.y; o[base + 2] = xq.z; o[base + 3] = xq.w;
    }
  }

  // ---- lorentz fusion (wave-local, no LDS) ----
#pragma unroll
  for (int p = 0; p < PPW; ++p) {
    float r2[4];
    {
      float pa[4];
#pragma unroll
      for (int c = 0; c < 4; ++c) pa[c] = dot4f(h[c][p], h[c][p]);
      wave_reduce<4>(pa);
#pragma unroll
      for (int c = 0; c < 4; ++c) r2[c] = pa[c];
    }
    // t0 = logmap(origin, y); wt = sum_c w_c t0_c
    float  wt0 = 0.f;
    float4 wtr = make_float4(0.f, 0.f, 0.f, 0.f);
#pragma unroll
    for (int c = 0; c < 4; ++c) {
      float y0    = x0s[c][p];
      float alpha = fmaxf(y0, 1.f + 1e-7f);
      float dist  = acoshf(alpha);
      float u0    = y0 - alpha;
      float msq   = r2[c] - u0 * u0;          // -u0^2 + ||yr||^2
      float un    = sqrtf(fmaxf(msq, 1e-12f));
      float f     = wgt[c] * dist / un;
      wt0 += f * u0;
      wtr.x += f * h[c][p].x; wtr.y += f * h[c][p].y;
      wtr.z += f * h[c][p].z; wtr.w += f * h[c][p].w;
    }
    float rr;
    { float t[1] = {dot4f(wtr, wtr)}; wave_reduce<1>(t); rr = t[0]; }
    float nrm = sqrtf(wt0 * wt0 + rr);        // clip norm incl comp 0
    float scl = fminf(nrm, 2.f) / fmaxf(nrm, 1e-12f);
    float nr  = scl * sqrtf(rr);              // spatial norm after clip
    float nsx = fmaxf(nr, 1e-9f);
    float sh  = sinhf(nr);
    float g   = sh * scl / nsx;
    float4 mr = make_float4(g * wtr.x, g * wtr.y, g * wtr.z, g * wtr.w);
    float mrr;
    { float t[1] = {dot4f(mr, mr)}; wave_reduce<1>(t); mrr = t[0]; }
    float m0 = sqrtf(1.f + mrr);              // projx

#pragma unroll 1
    for (int it = 0; it < 5; ++it) {
      float dots[4];
#pragma unroll
      for (int c = 0; c < 4; ++c) dots[c] = dot4f(mr, h[c][p]);
      wave_reduce<4>(dots);
      float  wv0 = 0.f;
      float4 wvr = make_float4(0.f, 0.f, 0.f, 0.f);
#pragma unroll
      for (int c = 0; c < 4; ++c) {
        float y0    = x0s[c][p];
        float ip    = m0 * y0 - dots[c];      // -mink(mean, y)
        float alpha = fmaxf(ip, 1.f + 1e-7f);
        float dist  = acoshf(alpha);
        float u0    = y0 - alpha * m0;
        // ||ur||^2 = r2 - 2*alpha*dot + alpha^2*||mr||^2 (algebraic)
        float s2  = r2[c] - 2.f * alpha * dots[c] + alpha * alpha * mrr;
        float msq = s2 - u0 * u0;
        float un  = sqrtf(fmaxf(msq, 1e-12f));
        float f   = wgt[c] * dist / un;
        wv0 += f * u0;
        wvr.x += f * (h[c][p].x - alpha * mr.x);
        wvr.y += f * (h[c][p].y - alpha * mr.y);
        wvr.z += f * (h[c][p].z - alpha * mr.z);
        wvr.w += f * (h[c][p].w - alpha * mr.w);
      }
      float rr2;
      { float t[1] = {dot4f(wvr, wvr)}; wave_reduce<1>(t); rr2 = t[0]; }
      float nrm2 = sqrtf(wv0 * wv0 + rr2);
      float sc2  = fminf(nrm2, 2.f) / fmaxf(nrm2, 1e-12f);
      float tt   = 0.1f * sc2;                // fold clip + 0.1 step
      float msqu = tt * tt * (rr2 - wv0 * wv0);  // mink(u,u)
      float un2  = sqrtf(fmaxf(msqu, 1e-12f));
      float shv  = sinhf(un2);
      float chv  = coshf(un2);
      float gg   = shv * tt / un2;
      mr.x = chv * mr.x + gg * wvr.x;
      mr.y = chv * mr.y + gg * wvr.y;
      mr.z = chv * mr.z + gg * wvr.z;
      mr.w = chv * mr.w + gg * wvr.w;
      { float t[1] = {dot4f(mr, mr)}; wave_reduce<1>(t); mrr = t[0]; }
      m0 = sqrtf(1.f + mrr);                  // projx (discards expmap x0)
    }

    float* o = out + 4 * HOFF + (size_t)(pt0 + p) * OUTS;
    if (lane == 0) o[0] = m0;
    int base = 1 + 4 * lane;
    o[base] = mr.x; o[base + 1] = mr.y; o[base + 2] = mr.z; o[base + 3] = mr.w;
  }
}

}  // namespace

extern "C" void kernel_launch(void* const* d_in, const int* in_sizes, int n_in,
                              void* d_out, int out_size, void* d_ws, size_t ws_size,
                              hipStream_t stream) {
  (void)in_sizes; (void)n_in; (void)out_size; (void)d_ws; (void)ws_size;
  splmw_kernel<<<GRID, 256, 0, stream>>>(
      (const float*)d_in[0], (const float*)d_in[1], (const float*)d_in[2],
      (const float*)d_in[3], (const float*)d_in[4], (const float*)d_in[5],
      (const float*)d_in[6], (const float*)d_in[7], (const float*)d_in[8],
      (const float*)d_in[9], (const float*)d_in[10], (const float*)d_in[11],
      (const float*)d_in[12], (const float*)d_in[13], (float*)d_out);
}

// Round 2
// 319.201 us; speedup vs baseline: 1.8757x; 1.8757x over previous
//
#include <hip/hip_runtime.h>
#include <math.h>

namespace {

typedef float f4 __attribute__((ext_vector_type(4)));

constexpr int PPW  = 4;                    // points per wave
constexpr int WPB  = 4;                    // waves per block
constexpr int PPB  = PPW * WPB;            // 16 points per block
constexpr int NPTS = 256 * 128;            // 32768 points total
constexpr int GRID = NPTS / PPB;           // 2048 blocks
constexpr int OUTS = 257;                  // D+1
constexpr size_t HOFF = (size_t)NPTS * OUTS;
constexpr int LSTR = 260;                  // LDS row stride (16B aligned)

__device__ __forceinline__ float frcp(float x)   { return __builtin_amdgcn_rcpf(x); }
__device__ __forceinline__ float fsqrt_(float x) { return __builtin_amdgcn_sqrtf(x); }
// acosh(a) = log(a + sqrt(a^2-1)); fma keeps a^2-1 accurate near a=1
__device__ __forceinline__ float facosh(float a) {
  return __logf(a + fsqrt_(fmaf(a, a, -1.f)));
}
__device__ __forceinline__ void fsinhcosh(float x, float& sh, float& ch) {
  float e = __expf(x), ei = frcp(e);
  sh = 0.5f * (e - ei);
  ch = 0.5f * (e + ei);
}
__device__ __forceinline__ float fsinh(float x) {
  float e = __expf(x);
  return 0.5f * (e - frcp(e));
}
__device__ __forceinline__ float dot4(f4 a, f4 b) {
  return a.x * b.x + a.y * b.y + a.z * b.z + a.w * b.w;
}
__device__ __forceinline__ f4 fma4s(float a, f4 b, f4 c) {
  f4 av = {a, a, a, a};
  return __builtin_elementwise_fma(av, b, c);
}

template <int NB>
__device__ __forceinline__ void wave_reduce(float* v) {
#pragma unroll
  for (int off = 32; off > 0; off >>= 1) {
#pragma unroll
    for (int i = 0; i < NB; ++i) v[i] += __shfl_xor(v[i], off, 64);
  }
}

__global__ __launch_bounds__(256) void splmw_kernel(
    const float* __restrict__ xt, const float* __restrict__ xc,
    const float* __restrict__ xf, const float* __restrict__ xr,
    const float* __restrict__ Wt, const float* __restrict__ bt,
    const float* __restrict__ Wc, const float* __restrict__ bc,
    const float* __restrict__ Wf, const float* __restrict__ bf,
    const float* __restrict__ Wr, const float* __restrict__ br,
    const float* __restrict__ esp, const float* __restrict__ lwp,
    float* __restrict__ out) {
  __shared__ float wlds[32 * LSTR];

  const int tid  = threadIdx.x;
  const int lane = tid & 63;
  const int wv   = __builtin_amdgcn_readfirstlane(tid >> 6);  // wave-uniform
  const int pt0  = blockIdx.x * PPB + wv * PPW;

  // tanh(effective_scale) via native exp
  float es2 = __expf(2.f * esp[0]);
  const float ts = (es2 - 1.f) * frcp(es2 + 1.f);
  // softmax of lorentz_weights
  float l0 = lwp[0], l1 = lwp[1], l2 = lwp[2], l3 = lwp[3];
  float mx = fmaxf(fmaxf(l0, l1), fmaxf(l2, l3));
  float e0 = __expf(l0 - mx), e1 = __expf(l1 - mx);
  float e2 = __expf(l2 - mx), e3 = __expf(l3 - mx);
  float ei = frcp(e0 + e1 + e2 + e3);
  const float wgt[4] = {e0 * ei, e1 * ei, e2 * ei, e3 * ei};

  const float* xsarr[4] = {xt, xc, xf, xr};
  const float* Wsarr[4] = {Wt, Wc, Wf, Wr};
  const float* Bsarr[4] = {bt, bc, bf, br};

  // h[c][p]: spatial fragment (comps 4*lane..4*lane+3)
  // x0s[c][p]: time component; r2s[c][p] = ||spatial||^2 (both wave-uniform)
  f4    h[4][PPW];
  float x0s[4][PPW];
  float r2s[4][PPW];

#pragma unroll
  for (int c = 0; c < 4; ++c) {
    // ---- stage W_c transposed into LDS: wlds[s*LSTR + d] = W[d][s] ----
    __syncthreads();
    {
      const float* Wp = Wsarr[c];
#pragma unroll
      for (int k = 0; k < 32; ++k) {
        int idx = k * 256 + tid;                       // flat d*32+s
        wlds[(idx & 31) * LSTR + (idx >> 5)] = Wp[idx];
      }
    }
    __syncthreads();

    // ---- encode: z[d] = sum_s xs[s]*W[d][s] + b[d], 4 points per wave ----
    const float* xp = xsarr[c] + (size_t)pt0 * 32;     // wave-uniform -> s_load
    {
      f4 bv = ((const f4*)Bsarr[c])[lane];
#pragma unroll
      for (int p = 0; p < PPW; ++p) h[c][p] = bv;
    }
#pragma unroll
    for (int s4 = 0; s4 < 8; ++s4) {
      f4 q0 = *(const f4*)(xp + 4 * s4);
      f4 q1 = *(const f4*)(xp + 32 + 4 * s4);
      f4 q2 = *(const f4*)(xp + 64 + 4 * s4);
      f4 q3 = *(const f4*)(xp + 96 + 4 * s4);
      float xv[4][4] = {{q0.x, q0.y, q0.z, q0.w}, {q1.x, q1.y, q1.z, q1.w},
                        {q2.x, q2.y, q2.z, q2.w}, {q3.x, q3.y, q3.z, q3.w}};
#pragma unroll
      for (int si = 0; si < 4; ++si) {
        int s = 4 * s4 + si;
        f4 w4 = *(const f4*)&wlds[s * LSTR + 4 * lane];
#pragma unroll
        for (int p = 0; p < PPW; ++p) h[c][p] = fma4s(xv[p][si], w4, h[c][p]);
      }
    }

    // ---- to_hyperbolic ----
    float pa[PPW];
#pragma unroll
    for (int p = 0; p < PPW; ++p) {
      h[c][p] = ts * h[c][p];
      pa[p]   = dot4(h[c][p], h[c][p]);
    }
    wave_reduce<PPW>(pa);
#pragma unroll
    for (int p = 0; p < PPW; ++p) {
      float n1  = fsqrt_(pa[p]);
      float n1m = fmaxf(n1, 1e-8f);
      float c1  = fminf(n1m, 1.5f) * frcp(n1m);   // clip-to-1.5 scale
      float n2  = c1 * n1;                        // norm after clip
      float nsx = fmaxf(n2, 1e-9f);
      float sh  = fsinh(n2);
      float rn  = frcp(nsx);
      float g   = sh * c1 * rn;
      f4 xq     = g * h[c][p];
      float sxr = sh * n2 * rn;                   // ||xr||
      float xx0 = fsqrt_(fmaf(sxr, sxr, 1.f));    // projx
      h[c][p]   = xq;
      x0s[c][p] = xx0;
      r2s[c][p] = g * g * pa[p];                  // ||xr||^2, algebraic
      float* o = out + (size_t)c * HOFF + (size_t)(pt0 + p) * OUTS;
      if (lane == 0) o[0] = xx0;
      int base = 1 + 4 * lane;
      o[base] = xq.x; o[base + 1] = xq.y; o[base + 2] = xq.z; o[base + 3] = xq.w;
    }
  }

  // ---- lorentz fusion: all PPW points advance together (batched reduces) ----
  float wt0[PPW];
  f4    wtr[PPW];
#pragma unroll
  for (int p = 0; p < PPW; ++p) {
    wt0[p] = 0.f;
    wtr[p] = (f4){0.f, 0.f, 0.f, 0.f};
#pragma unroll
    for (int c = 0; c < 4; ++c) {
      float y0    = x0s[c][p];
      float alpha = fmaxf(y0, 1.f + 1e-7f);
      float dist  = facosh(alpha);
      float u0    = y0 - alpha;
      float msq   = r2s[c][p] - u0 * u0;
      float un    = fsqrt_(fmaxf(msq, 1e-12f));
      float f     = wgt[c] * dist * frcp(un);
      wt0[p] = fmaf(f, u0, wt0[p]);
      wtr[p] = fma4s(f, h[c][p], wtr[p]);
    }
  }
  float rrp[PPW];
#pragma unroll
  for (int p = 0; p < PPW; ++p) rrp[p] = dot4(wtr[p], wtr[p]);
  wave_reduce<PPW>(rrp);

  f4    mr[PPW];
  float mrr[PPW], m0[PPW];
#pragma unroll
  for (int p = 0; p < PPW; ++p) {
    float rr  = rrp[p];
    float nrm = fsqrt_(fmaf(wt0[p], wt0[p], rr));
    float scl = fminf(nrm, 2.f) * frcp(fmaxf(nrm, 1e-12f));
    float nr  = scl * fsqrt_(rr);                 // spatial norm after clip
    float nsx = fmaxf(nr, 1e-9f);
    float g   = fsinh(nr) * scl * frcp(nsx);
    mr[p]  = g * wtr[p];
    mrr[p] = g * g * rr;                          // ||mr||^2, algebraic
    m0[p]  = fsqrt_(1.f + mrr[p]);                // projx
  }

#pragma unroll 1
  for (int it = 0; it < 5; ++it) {
    float dots[4 * PPW];
#pragma unroll
    for (int p = 0; p < PPW; ++p)
#pragma unroll
      for (int c = 0; c < 4; ++c) dots[p * 4 + c] = dot4(mr[p], h[c][p]);
    wave_reduce<4 * PPW>(dots);

    float wv0[PPW];
    f4    wvr[PPW];
#pragma unroll
    for (int p = 0; p < PPW; ++p) {
      wv0[p] = 0.f;
      wvr[p] = (f4){0.f, 0.f, 0.f, 0.f};
#pragma unroll
      for (int c = 0; c < 4; ++c) {
        float d     = dots[p * 4 + c];
        float y0    = x0s[c][p];
        float ip    = fmaf(m0[p], y0, -d);        // -mink(mean, y)
        float alpha = fmaxf(ip, 1.f + 1e-7f);
        float dist  = facosh(alpha);
        float u0    = fmaf(-alpha, m0[p], y0);
        // ||ur||^2 = r2 - 2*alpha*dot + alpha^2*mrr (algebraic)
        float t   = fmaf(alpha, mrr[p], -2.f * d);
        float s2  = fmaf(alpha, t, r2s[c][p]);
        float msq = s2 - u0 * u0;
        float un  = fsqrt_(fmaxf(msq, 1e-12f));
        float f   = wgt[c] * dist * frcp(un);
        wv0[p] = fmaf(f, u0, wv0[p]);
        f4 diff = fma4s(-alpha, mr[p], h[c][p]);
        wvr[p]  = fma4s(f, diff, wvr[p]);
      }
    }
    float pr[2 * PPW];
#pragma unroll
    for (int p = 0; p < PPW; ++p) {
      pr[p]       = dot4(wvr[p], wvr[p]);
      pr[PPW + p] = dot4(mr[p], wvr[p]);
    }
    wave_reduce<2 * PPW>(pr);

#pragma unroll
    for (int p = 0; p < PPW; ++p) {
      float rr2  = pr[p];
      float mwv  = pr[PPW + p];
      float nrm2 = fsqrt_(fmaf(wv0[p], wv0[p], rr2));
      float sc2  = fminf(nrm2, 2.f) * frcp(fmaxf(nrm2, 1e-12f));
      float tt   = 0.1f * sc2;                    // fold clip + 0.1 step
      float msqu = tt * tt * (rr2 - wv0[p] * wv0[p]);  // mink(u,u)
      float un2  = fsqrt_(fmaxf(msqu, 1e-12f));
      float shv, chv;
      fsinhcosh(un2, shv, chv);
      float gg = shv * tt * frcp(un2);
      mr[p] = fma4s(chv, mr[p], gg * wvr[p]);
      // ||mr'||^2 = chv^2*mrr + 2*chv*gg*(mr.wvr) + gg^2*rr2 (algebraic)
      mrr[p] = chv * chv * mrr[p] + 2.f * chv * gg * mwv + gg * gg * rr2;
      m0[p]  = fsqrt_(1.f + mrr[p]);              // projx
    }
  }

#pragma unroll
  for (int p = 0; p < PPW; ++p) {
    float* o = out + 4 * HOFF + (size_t)(pt0 + p) * OUTS;
    if (lane == 0) o[0] = m0[p];
    int base = 1 + 4 * lane;
    f4 v = mr[p];
    o[base] = v.x; o[base + 1] = v.y; o[base + 2] = v.z; o[base + 3] = v.w;
  }
}

}  // namespace

extern "C" void kernel_launch(void* const* d_in, const int* in_sizes, int n_in,
                              void* d_out, int out_size, void* d_ws, size_t ws_size,
                              hipStream_t stream) {
  (void)in_sizes; (void)n_in; (void)out_size; (void)d_ws; (void)ws_size;
  splmw_kernel<<<GRID, 256, 0, stream>>>(
      (const float*)d_in[0], (const float*)d_in[1], (const float*)d_in[2],
      (const float*)d_in[3], (const float*)d_in[4], (const float*)d_in[5],
      (const float*)d_in[6], (const float*)d_in[7], (const float*)d_in[8],
      (const float*)d_in[9], (const float*)d_in[10], (const float*)d_in[11],
      (const float*)d_in[12], (const float*)d_in[13], (float*)d_out);
}